// Round 5
// baseline (699.009 us; speedup 1.0000x reference)
//
#include <hip/hip_runtime.h>
#include <hip/hip_bf16.h>
#include <cstddef>

// Bn=256, N=197, C=192, H=3, hd=64, E=1024, hid=768, M = Bn*N = 50432 = 394*128
//
// ws layout (bytes):
//   [0,          77463552)   : h1 bf16 [50432][768]
//   [77463552,  116195328)   : qk  bf16 [50432][384]   (Q cols 0..191, K cols 192..383)
//   [116195328, 135561216)   : xn  bf16 [50432][192]   (reused as x2n after proj)
//   [135561216, 154927104)   : agg bf16 [50432][192]
//   [154927104, 174587904)   : vt  bf16 [256][3][64][200]  (V transposed, t contiguous)
//   [174587904, 175472640)   : bf16 weights (qkv, proj, fc1, fc2)
//   [175472640, 175473664)   : cnt int32[256]

typedef __attribute__((ext_vector_type(8))) short bf8_t;
typedef __attribute__((ext_vector_type(4))) float f4_t;

__device__ __forceinline__ float bf2f(unsigned short u) {
  union { unsigned int i; float f; } x; x.i = ((unsigned int)u) << 16; return x.f;
}
__device__ __forceinline__ unsigned short f2bf(float f) {
  unsigned int u = __builtin_bit_cast(unsigned int, f);
  u = (u + 0x7FFFu + ((u >> 16) & 1u)) >> 16;
  return (unsigned short)u;
}

// ---------------------------------------------------------------------------
__global__ __launch_bounds__(256) void f2bf_kernel(const float* __restrict__ src,
                                                   unsigned short* __restrict__ dst, int n) {
  int i = blockIdx.x * 256 + threadIdx.x;
  if (i < n) dst[i] = f2bf(src[i]);
}

// ---------------------------------------------------------------------------
// LayerNorm(fp32 in) -> bf16 out.  One wave per row (C=192, 3 elems/lane).
// ---------------------------------------------------------------------------
__global__ __launch_bounds__(256) void ln_bf16_kernel(const float* __restrict__ X,
    const float* __restrict__ g, const float* __restrict__ b,
    unsigned short* __restrict__ Y) {
  int row = blockIdx.x * 4 + (threadIdx.x >> 6);
  int lane = threadIdx.x & 63;
  const float* xr = X + (size_t)row * 192;
  float v0 = xr[lane], v1 = xr[lane + 64], v2 = xr[lane + 128];
  float s = v0 + v1 + v2, ss = v0 * v0 + v1 * v1 + v2 * v2;
#pragma unroll
  for (int o = 32; o > 0; o >>= 1) { s += __shfl_xor(s, o, 64); ss += __shfl_xor(ss, o, 64); }
  float mean = s * (1.f / 192.f);
  float var = ss * (1.f / 192.f) - mean * mean;
  float r = rsqrtf(var + 1e-5f);
  unsigned short* yr = Y + (size_t)row * 192;
  yr[lane]       = f2bf((v0 - mean) * r * g[lane]       + b[lane]);
  yr[lane + 64]  = f2bf((v1 - mean) * r * g[lane + 64]  + b[lane + 64]);
  yr[lane + 128] = f2bf((v2 - mean) * r * g[lane + 128] + b[lane + 128]);
}

// ---------------------------------------------------------------------------
// bf16 MFMA GEMM: C = f( A @ W^T ), tile 128x64, 4 waves.
// MODE 0: qkv -> qk bf16 (cols<384) + vt bf16 transposed (cols>=384)
// MODE 1: proj -> f32 (/cnt, +bias, +xres)
// MODE 2: fc1 -> bf16 gelu(+bias)
// MODE 3: fc2 -> f32 (+bias, +xres; in-place safe per-element)
// ---------------------------------------------------------------------------
template<int MODE, int NK>
__global__ __launch_bounds__(256) void gemm_bf16(
    const unsigned short* __restrict__ A, const unsigned short* __restrict__ W,
    const float* __restrict__ bias, const float* __restrict__ xres,
    const int* __restrict__ cntg, void* __restrict__ Cout,
    unsigned short* __restrict__ Cvt, int ldc) {
  constexpr int LDA = 200;
  __shared__ unsigned short As[128 * LDA];
  __shared__ unsigned short Ws[64 * LDA];
  const int tid = threadIdx.x;
  const int m0 = blockIdx.x * 128, n0 = blockIdx.y * 64;
  const int wave = tid >> 6, lane = tid & 63;
  const int mfrag = lane & 15, quad = lane >> 4;
  const int K = NK * 192;

  f4_t acc[2][4];
#pragma unroll
  for (int i = 0; i < 2; ++i)
#pragma unroll
    for (int j = 0; j < 4; ++j) acc[i][j] = (f4_t){0.f, 0.f, 0.f, 0.f};

  for (int kc = 0; kc < NK; ++kc) {
    __syncthreads();
#pragma unroll
    for (int it = 0; it < 12; ++it) {
      int idx = it * 256 + tid;
      int r = idx / 24, c = idx % 24;
      *(float4*)(As + r * LDA + c * 8) =
          *(const float4*)(A + (size_t)(m0 + r) * K + kc * 192 + c * 8);
    }
#pragma unroll
    for (int it = 0; it < 6; ++it) {
      int idx = it * 256 + tid;
      int r = idx / 24, c = idx % 24;
      *(float4*)(Ws + r * LDA + c * 8) =
          *(const float4*)(W + (size_t)(n0 + r) * K + kc * 192 + c * 8);
    }
    __syncthreads();
#pragma unroll
    for (int ks = 0; ks < 6; ++ks) {
      bf8_t a0 = *(const bf8_t*)(As + (wave * 32 + mfrag) * LDA + ks * 32 + quad * 8);
      bf8_t a1 = *(const bf8_t*)(As + (wave * 32 + 16 + mfrag) * LDA + ks * 32 + quad * 8);
#pragma unroll
      for (int nt = 0; nt < 4; ++nt) {
        bf8_t bf = *(const bf8_t*)(Ws + (nt * 16 + mfrag) * LDA + ks * 32 + quad * 8);
        acc[0][nt] = __builtin_amdgcn_mfma_f32_16x16x32_bf16(a0, bf, acc[0][nt], 0, 0, 0);
        acc[1][nt] = __builtin_amdgcn_mfma_f32_16x16x32_bf16(a1, bf, acc[1][nt], 0, 0, 0);
      }
    }
  }

#pragma unroll
  for (int mt = 0; mt < 2; ++mt)
#pragma unroll
    for (int nt = 0; nt < 4; ++nt)
#pragma unroll
      for (int reg = 0; reg < 4; ++reg) {
        int row = m0 + wave * 32 + mt * 16 + quad * 4 + reg;
        int col = n0 + nt * 16 + mfrag;
        float v = acc[mt][nt][reg];
        if constexpr (MODE == 0) {
          if (col < 384) {
            ((unsigned short*)Cout)[(size_t)row * 384 + col] = f2bf(v);
          } else {
            int cc = col - 384, hh = cc >> 6, dd = cc & 63;
            int bb = row / 197, tt = row - bb * 197;
            Cvt[((size_t)(bb * 3 + hh) * 64 + dd) * 200 + tt] = f2bf(v);
          }
        } else if constexpr (MODE == 1) {
          int c = cntg[row / 197];
          v = (c > 0) ? v / (float)c + bias[col] : 0.f;
          v += xres[(size_t)row * 192 + col];
          ((float*)Cout)[(size_t)row * ldc + col] = v;
        } else if constexpr (MODE == 2) {
          v += bias[col];
          v = 0.5f * v * (1.f + erff(v * 0.70710678118654752f));
          ((unsigned short*)Cout)[(size_t)row * ldc + col] = f2bf(v);
        } else {
          v += bias[col] + xres[(size_t)row * 192 + col];
          ((float*)Cout)[(size_t)row * ldc + col] = v;
        }
      }
}

// ---------------------------------------------------------------------------
// Fused attention+aggregation: one block per (dst b, head h).
// agg[b] = (sum_e softmax(Q_b K_{s_e}^T/8)) @ V_b  -- PV hoisted out of edge loop.
// Psum accumulates in REGISTERS (per-wave strips); 2 passes (strips 0..6 / 7..12)
// keep Pacc <= 2x13 f4 = 104 VGPRs.  K staged per edge per pass (L2-absorbed).
// ---------------------------------------------------------------------------
__global__ __launch_bounds__(256, 2) void attn_fused_kernel(
    const unsigned short* __restrict__ qk, const unsigned short* __restrict__ vtg,
    const int* __restrict__ edge, unsigned short* __restrict__ agg,
    int* __restrict__ cntg) {
  const int b = blockIdx.x, h = blockIdx.y;
  __shared__ unsigned short Ks[208 * 72];
  __shared__ unsigned short Vt[64 * 232];
  __shared__ unsigned short Ps[4][2][640];   // [wave][parity][16*40]
  __shared__ int list[1024];
  __shared__ int lc;
  const int tid = threadIdx.x;
  const int wave = tid >> 6, lane = tid & 63;
  const int mfrag = lane & 15, quad = lane >> 4;

  if (tid == 0) lc = 0;
  __syncthreads();
  for (int e = tid; e < 1024; e += 256)
    if (edge[1024 + e] == b) { int p = atomicAdd(&lc, 1); list[p] = edge[e]; }
  // stage V^T rows (dst b) from pre-transposed global, b128 conflict-free
  for (int i = tid; i < 64 * 25; i += 256) {
    int d = i / 25, c8 = i - d * 25;
    *(float4*)(Vt + d * 232 + c8 * 8) =
        *(const float4*)(vtg + ((size_t)(b * 3 + h) * 64 + d) * 200 + c8 * 8);
  }
  __syncthreads();   // scan + Vt main done
  // zero pad keys 197..231 (197..199 overwrite staged garbage)
  for (int i = tid; i < 64 * 35; i += 256) {
    int d = i / 35, kk = 197 + (i - d * 35);
    Vt[d * 232 + kk] = 0;
  }
  const int cnt = lc;
  if (h == 0 && tid == 0) cntg[b] = cnt;
  __syncthreads();
  if (cnt == 0) return;   // agg rows discarded downstream (proj zeroes on cnt==0)

#pragma unroll 1
  for (int pass = 0; pass < 2; ++pass) {
    const int s0 = (pass == 0) ? wave : 7 + wave;
    const int s1 = (pass == 0) ? wave + 4 : 11 + wave;
    const int ns = (pass == 0) ? ((s1 < 7) ? 2 : 1) : ((s1 < 13) ? 2 : 1);

    // Q fragments for my strips (rows clamped; clamped rows masked at store)
    bf8_t qa0[2], qa1[2];
#pragma unroll
    for (int si = 0; si < 2; ++si) {
      int strip = (si == 0) ? s0 : s1;
      if (si < ns) {
        const size_t qrow = (size_t)(b * 197 + min(strip * 16 + mfrag, 196)) * 384 + h * 64;
        qa0[si] = *(const bf8_t*)(qk + qrow + quad * 8);
        qa1[si] = *(const bf8_t*)(qk + qrow + 32 + quad * 8);
      }
    }

    f4_t Pacc[2][13];
#pragma unroll
    for (int si = 0; si < 2; ++si)
#pragma unroll
      for (int nt = 0; nt < 13; ++nt) Pacc[si][nt] = (f4_t){0.f, 0.f, 0.f, 0.f};

    for (int ei = 0; ei < cnt; ++ei) {
      const int s = list[ei];
      __syncthreads();   // prior S-reads of Ks done
      for (int i = tid; i < 197 * 8; i += 256) {
        int m = i >> 3, c8 = i & 7;
        *(float4*)(Ks + m * 72 + c8 * 8) =
            *(const float4*)(qk + (size_t)(s * 197 + m) * 384 + 192 + h * 64 + c8 * 8);
      }
      __syncthreads();

#pragma unroll
      for (int si = 0; si < 2; ++si) {
        if (si >= ns) continue;
        f4_t S[13];
#pragma unroll
        for (int nt = 0; nt < 13; ++nt) {
          bf8_t k0 = *(const bf8_t*)(Ks + (nt * 16 + mfrag) * 72 + quad * 8);
          bf8_t k1 = *(const bf8_t*)(Ks + (nt * 16 + mfrag) * 72 + 32 + quad * 8);
          f4_t z = (f4_t){0.f, 0.f, 0.f, 0.f};
          z = __builtin_amdgcn_mfma_f32_16x16x32_bf16(qa0[si], k0, z, 0, 0, 0);
          S[nt] = __builtin_amdgcn_mfma_f32_16x16x32_bf16(qa1[si], k1, z, 0, 0, 0);
        }
        // exact softmax over keys; lane holds S[q=quad*4+reg][key=nt*16+mfrag]
        float mx[4] = {-1e30f, -1e30f, -1e30f, -1e30f};
#pragma unroll
        for (int nt = 0; nt < 13; ++nt) {
          int key = nt * 16 + mfrag;
#pragma unroll
          for (int reg = 0; reg < 4; ++reg) {
            float v = (key < 197) ? S[nt][reg] * 0.125f : -1e30f;
            S[nt][reg] = v;
            mx[reg] = fmaxf(mx[reg], v);
          }
        }
#pragma unroll
        for (int off = 1; off < 16; off <<= 1)
#pragma unroll
          for (int reg = 0; reg < 4; ++reg) mx[reg] = fmaxf(mx[reg], __shfl_xor(mx[reg], off, 64));
        float sum[4] = {0.f, 0.f, 0.f, 0.f};
#pragma unroll
        for (int nt = 0; nt < 13; ++nt)
#pragma unroll
          for (int reg = 0; reg < 4; ++reg) {
            float p = __expf(S[nt][reg] - mx[reg]);
            S[nt][reg] = p;
            sum[reg] += p;
          }
#pragma unroll
        for (int off = 1; off < 16; off <<= 1)
#pragma unroll
          for (int reg = 0; reg < 4; ++reg) sum[reg] += __shfl_xor(sum[reg], off, 64);
        float inv[4];
#pragma unroll
        for (int reg = 0; reg < 4; ++reg) inv[reg] = 1.f / sum[reg];
#pragma unroll
        for (int nt = 0; nt < 13; ++nt)
#pragma unroll
          for (int reg = 0; reg < 4; ++reg)
            Pacc[si][nt][reg] += S[nt][reg] * inv[reg];
      }
    }

    // PV once per strip: Pacc -> LDS (wave-private dbuf) -> A-frag -> MFMA vs V^T
#pragma unroll
    for (int si = 0; si < 2; ++si) {
      if (si >= ns) continue;
      const int strip = (si == 0) ? s0 : s1;
      f4_t o[4];
#pragma unroll
      for (int dt = 0; dt < 4; ++dt) o[dt] = (f4_t){0.f, 0.f, 0.f, 0.f};
#pragma unroll
      for (int kt = 0; kt < 7; ++kt) {
        unsigned short* buf = Ps[wave][kt & 1];
#pragma unroll
        for (int half = 0; half < 2; ++half) {
          int nt = kt * 2 + half;
#pragma unroll
          for (int reg = 0; reg < 4; ++reg) {
            float p = (nt < 13) ? Pacc[si][nt][reg] : 0.f;
            buf[(quad * 4 + reg) * 40 + half * 16 + mfrag] = f2bf(p);
          }
        }
        bf8_t pf = *(const bf8_t*)(buf + mfrag * 40 + quad * 8);
#pragma unroll
        for (int dt = 0; dt < 4; ++dt) {
          bf8_t vf = *(const bf8_t*)(Vt + (dt * 16 + mfrag) * 232 + kt * 32 + quad * 8);
          o[dt] = __builtin_amdgcn_mfma_f32_16x16x32_bf16(pf, vf, o[dt], 0, 0, 0);
        }
      }
#pragma unroll
      for (int dt = 0; dt < 4; ++dt)
#pragma unroll
        for (int reg = 0; reg < 4; ++reg) {
          int q = strip * 16 + quad * 4 + reg;
          if (q < 197)
            agg[(size_t)(b * 197 + q) * 192 + h * 64 + dt * 16 + mfrag] = f2bf(o[dt][reg]);
        }
    }
  }
}

// ---------------------------------------------------------------------------
extern "C" void kernel_launch(void* const* d_in, const int* in_sizes, int n_in,
                              void* d_out, int out_size, void* d_ws, size_t ws_size,
                              hipStream_t stream) {
  const float* x      = (const float*)d_in[0];
  const int*   edge   = (const int*)d_in[1];
  const float* n1g    = (const float*)d_in[2];
  const float* n1b    = (const float*)d_in[3];
  const float* qkv_w  = (const float*)d_in[4];
  const float* proj_w = (const float*)d_in[5];
  const float* proj_b = (const float*)d_in[6];
  const float* n2g    = (const float*)d_in[7];
  const float* n2b    = (const float*)d_in[8];
  const float* fc1_w  = (const float*)d_in[9];
  const float* fc1_b  = (const float*)d_in[10];
  const float* fc2_w  = (const float*)d_in[11];
  const float* fc2_b  = (const float*)d_in[12];
  float* out = (float*)d_out;

  char* ws = (char*)d_ws;
  unsigned short* h1     = (unsigned short*)ws;
  unsigned short* qk     = (unsigned short*)(ws + 77463552);
  unsigned short* xn     = (unsigned short*)(ws + 116195328);
  unsigned short* agg    = (unsigned short*)(ws + 135561216);
  unsigned short* vtg    = (unsigned short*)(ws + 154927104);
  unsigned short* wqkv   = (unsigned short*)(ws + 174587904);
  unsigned short* wproj  = (unsigned short*)(ws + 174809088);
  unsigned short* wfc1   = (unsigned short*)(ws + 174882816);
  unsigned short* wfc2   = (unsigned short*)(ws + 175177728);
  int*            cntg   = (int*)           (ws + 175472640);

  dim3 blk(256);
  f2bf_kernel<<<dim3(432), blk, 0, stream>>>(qkv_w, wqkv, 110592);
  f2bf_kernel<<<dim3(144), blk, 0, stream>>>(proj_w, wproj, 36864);
  f2bf_kernel<<<dim3(576), blk, 0, stream>>>(fc1_w, wfc1, 147456);
  f2bf_kernel<<<dim3(576), blk, 0, stream>>>(fc2_w, wfc2, 147456);

  ln_bf16_kernel<<<dim3(12608), blk, 0, stream>>>(x, n1g, n1b, xn);
  gemm_bf16<0, 1><<<dim3(394, 9), blk, 0, stream>>>(xn, wqkv, nullptr, nullptr, nullptr, qk, vtg, 384);
  attn_fused_kernel<<<dim3(256, 3), blk, 0, stream>>>(qk, vtg, edge, agg, cntg);
  gemm_bf16<1, 1><<<dim3(394, 3), blk, 0, stream>>>(agg, wproj, proj_b, x, cntg, out, nullptr, 192);
  ln_bf16_kernel<<<dim3(12608), blk, 0, stream>>>(out, n2g, n2b, xn);
  gemm_bf16<2, 1><<<dim3(394, 12), blk, 0, stream>>>(xn, wfc1, fc1_b, nullptr, nullptr, h1, nullptr, 768);
  gemm_bf16<3, 4><<<dim3(394, 3), blk, 0, stream>>>(h1, wfc2, fc2_b, out, nullptr, out, nullptr, 192);
}

// Round 6
// 531.571 us; speedup vs baseline: 1.3150x; 1.3150x over previous
//
#include <hip/hip_runtime.h>
#include <hip/hip_bf16.h>
#include <cstddef>

// Bn=256, N=197, C=192, H=3, hd=64, E=1024, hid=768, M = Bn*N = 50432 = 394*128
//
// ws layout (bytes):
//   [0,          77463552)   : h1 bf16 [50432][768]
//   [77463552,  116195328)   : qk  bf16 [50432][384]   (Q cols 0..191, K cols 192..383)
//   [116195328, 135561216)   : xn  bf16 [50432][192]   (reused as x2n after proj)
//   [135561216, 154927104)   : agg bf16 [50432][192]
//   [154927104, 174587904)   : vt  bf16 [256][3][64][200]  (V transposed, t contiguous)
//   [174587904, 175472640)   : bf16 weights (qkv, proj, fc1, fc2)
//   [175472640, 175473664)   : cnt int32[256]

typedef __attribute__((ext_vector_type(8))) short bf8_t;
typedef __attribute__((ext_vector_type(4))) float f4_t;

__device__ __forceinline__ float bf2f(unsigned short u) {
  union { unsigned int i; float f; } x; x.i = ((unsigned int)u) << 16; return x.f;
}
__device__ __forceinline__ unsigned short f2bf(float f) {
  unsigned int u = __builtin_bit_cast(unsigned int, f);
  u = (u + 0x7FFFu + ((u >> 16) & 1u)) >> 16;
  return (unsigned short)u;
}

// ---------------------------------------------------------------------------
__global__ __launch_bounds__(256) void f2bf_kernel(const float* __restrict__ src,
                                                   unsigned short* __restrict__ dst, int n) {
  int i = blockIdx.x * 256 + threadIdx.x;
  if (i < n) dst[i] = f2bf(src[i]);
}

// ---------------------------------------------------------------------------
// LayerNorm(fp32 in) -> bf16 out.  One wave per row (C=192, 3 elems/lane).
// ---------------------------------------------------------------------------
__global__ __launch_bounds__(256) void ln_bf16_kernel(const float* __restrict__ X,
    const float* __restrict__ g, const float* __restrict__ b,
    unsigned short* __restrict__ Y) {
  int row = blockIdx.x * 4 + (threadIdx.x >> 6);
  int lane = threadIdx.x & 63;
  const float* xr = X + (size_t)row * 192;
  float v0 = xr[lane], v1 = xr[lane + 64], v2 = xr[lane + 128];
  float s = v0 + v1 + v2, ss = v0 * v0 + v1 * v1 + v2 * v2;
#pragma unroll
  for (int o = 32; o > 0; o >>= 1) { s += __shfl_xor(s, o, 64); ss += __shfl_xor(ss, o, 64); }
  float mean = s * (1.f / 192.f);
  float var = ss * (1.f / 192.f) - mean * mean;
  float r = rsqrtf(var + 1e-5f);
  unsigned short* yr = Y + (size_t)row * 192;
  yr[lane]       = f2bf((v0 - mean) * r * g[lane]       + b[lane]);
  yr[lane + 64]  = f2bf((v1 - mean) * r * g[lane + 64]  + b[lane + 64]);
  yr[lane + 128] = f2bf((v2 - mean) * r * g[lane + 128] + b[lane + 128]);
}

// ---------------------------------------------------------------------------
// bf16 MFMA GEMM: C = f( A @ W^T ), tile 128x64, 4 waves.
// MODE 0: qkv -> qk bf16 (cols<384) + vt bf16 transposed (cols>=384)
// MODE 1: proj -> f32 (/cnt, +bias, +xres)
// MODE 2: fc1 -> bf16 gelu(+bias)
// MODE 3: fc2 -> f32 (+bias, +xres; in-place safe per-element)
// ---------------------------------------------------------------------------
template<int MODE, int NK>
__global__ __launch_bounds__(256) void gemm_bf16(
    const unsigned short* __restrict__ A, const unsigned short* __restrict__ W,
    const float* __restrict__ bias, const float* __restrict__ xres,
    const int* __restrict__ cntg, void* __restrict__ Cout,
    unsigned short* __restrict__ Cvt, int ldc) {
  constexpr int LDA = 200;
  __shared__ unsigned short As[128 * LDA];
  __shared__ unsigned short Ws[64 * LDA];
  const int tid = threadIdx.x;
  const int m0 = blockIdx.x * 128, n0 = blockIdx.y * 64;
  const int wave = tid >> 6, lane = tid & 63;
  const int mfrag = lane & 15, quad = lane >> 4;
  const int K = NK * 192;

  f4_t acc[2][4];
#pragma unroll
  for (int i = 0; i < 2; ++i)
#pragma unroll
    for (int j = 0; j < 4; ++j) acc[i][j] = (f4_t){0.f, 0.f, 0.f, 0.f};

  for (int kc = 0; kc < NK; ++kc) {
    __syncthreads();
#pragma unroll
    for (int it = 0; it < 12; ++it) {
      int idx = it * 256 + tid;
      int r = idx / 24, c = idx % 24;
      *(float4*)(As + r * LDA + c * 8) =
          *(const float4*)(A + (size_t)(m0 + r) * K + kc * 192 + c * 8);
    }
#pragma unroll
    for (int it = 0; it < 6; ++it) {
      int idx = it * 256 + tid;
      int r = idx / 24, c = idx % 24;
      *(float4*)(Ws + r * LDA + c * 8) =
          *(const float4*)(W + (size_t)(n0 + r) * K + kc * 192 + c * 8);
    }
    __syncthreads();
#pragma unroll
    for (int ks = 0; ks < 6; ++ks) {
      bf8_t a0 = *(const bf8_t*)(As + (wave * 32 + mfrag) * LDA + ks * 32 + quad * 8);
      bf8_t a1 = *(const bf8_t*)(As + (wave * 32 + 16 + mfrag) * LDA + ks * 32 + quad * 8);
#pragma unroll
      for (int nt = 0; nt < 4; ++nt) {
        bf8_t bf = *(const bf8_t*)(Ws + (nt * 16 + mfrag) * LDA + ks * 32 + quad * 8);
        acc[0][nt] = __builtin_amdgcn_mfma_f32_16x16x32_bf16(a0, bf, acc[0][nt], 0, 0, 0);
        acc[1][nt] = __builtin_amdgcn_mfma_f32_16x16x32_bf16(a1, bf, acc[1][nt], 0, 0, 0);
      }
    }
  }

#pragma unroll
  for (int mt = 0; mt < 2; ++mt)
#pragma unroll
    for (int nt = 0; nt < 4; ++nt)
#pragma unroll
      for (int reg = 0; reg < 4; ++reg) {
        int row = m0 + wave * 32 + mt * 16 + quad * 4 + reg;
        int col = n0 + nt * 16 + mfrag;
        float v = acc[mt][nt][reg];
        if constexpr (MODE == 0) {
          if (col < 384) {
            ((unsigned short*)Cout)[(size_t)row * 384 + col] = f2bf(v);
          } else {
            int cc = col - 384, hh = cc >> 6, dd = cc & 63;
            int bb = row / 197, tt = row - bb * 197;
            Cvt[((size_t)(bb * 3 + hh) * 64 + dd) * 200 + tt] = f2bf(v);
          }
        } else if constexpr (MODE == 1) {
          int c = cntg[row / 197];
          v = (c > 0) ? v / (float)c + bias[col] : 0.f;
          v += xres[(size_t)row * 192 + col];
          ((float*)Cout)[(size_t)row * ldc + col] = v;
        } else if constexpr (MODE == 2) {
          v += bias[col];
          v = 0.5f * v * (1.f + erff(v * 0.70710678118654752f));
          ((unsigned short*)Cout)[(size_t)row * ldc + col] = f2bf(v);
        } else {
          v += bias[col] + xres[(size_t)row * 192 + col];
          ((float*)Cout)[(size_t)row * ldc + col] = v;
        }
      }
}

// ---------------------------------------------------------------------------
// Fused attention+aggregation.  Grid (256 dst, 3 heads, 4 strip-groups).
// Block (b,h,g) computes agg strips s in {g, g+4, g+8, g+12} (s<13): wave w owns
// strip g+4w.  Pacc (13 f4 = 52 VGPRs) accumulates sum_e softmax(Q K_e^T/8)
// per strip in registers; ONE PV per strip at the end (hoisted: V is dst-side).
// No launch_bounds VGPR cap -- R5's (256,2) caused catastrophic scratch spill.
// ---------------------------------------------------------------------------
__global__ __launch_bounds__(256) void attn_fused_kernel(
    const unsigned short* __restrict__ qk, const unsigned short* __restrict__ vtg,
    const int* __restrict__ edge, unsigned short* __restrict__ agg,
    int* __restrict__ cntg) {
  const int b = blockIdx.x, h = blockIdx.y, g = blockIdx.z;
  __shared__ unsigned short Ks[208 * 72];
  __shared__ unsigned short Vt[64 * 232];
  __shared__ unsigned short Ps[4][2][640];   // [wave][parity][16*40]
  __shared__ int list[1024];
  __shared__ int lc;
  const int tid = threadIdx.x;
  const int wave = tid >> 6, lane = tid & 63;
  const int mfrag = lane & 15, quad = lane >> 4;

  if (tid == 0) lc = 0;
  __syncthreads();
  for (int e = tid; e < 1024; e += 256)
    if (edge[1024 + e] == b) { int p = atomicAdd(&lc, 1); list[p] = edge[e]; }
  // stage V^T rows (dst b) from pre-transposed global, b128 conflict-free
  for (int i = tid; i < 64 * 25; i += 256) {
    int d = i / 25, c8 = i - d * 25;
    *(float4*)(Vt + d * 232 + c8 * 8) =
        *(const float4*)(vtg + ((size_t)(b * 3 + h) * 64 + d) * 200 + c8 * 8);
  }
  __syncthreads();   // scan + Vt main done
  // zero pad keys 197..231 (197..199 overwrite staged garbage)
  for (int i = tid; i < 64 * 35; i += 256) {
    int d = i / 35, kk = 197 + (i - d * 35);
    Vt[d * 232 + kk] = 0;
  }
  const int cnt = lc;
  if (h == 0 && g == 0 && tid == 0) cntg[b] = cnt;
  __syncthreads();
  if (cnt == 0) return;   // agg rows ignored downstream (proj zeroes on cnt==0)

  const int strip = g + 4 * wave;          // one strip per wave, or none
  const bool has = (strip < 13);

  // Q fragments for my strip (rows clamped; clamped rows masked at store)
  bf8_t qa0, qa1;
  if (has) {
    const size_t qrow = (size_t)(b * 197 + min(strip * 16 + mfrag, 196)) * 384 + h * 64;
    qa0 = *(const bf8_t*)(qk + qrow + quad * 8);
    qa1 = *(const bf8_t*)(qk + qrow + 32 + quad * 8);
  }

  f4_t Pacc[13];
#pragma unroll
  for (int nt = 0; nt < 13; ++nt) Pacc[nt] = (f4_t){0.f, 0.f, 0.f, 0.f};

  for (int ei = 0; ei < cnt; ++ei) {
    const int s = list[ei];
    __syncthreads();   // prior S-reads of Ks done
    for (int i = tid; i < 197 * 8; i += 256) {
      int m = i >> 3, c8 = i & 7;
      *(float4*)(Ks + m * 72 + c8 * 8) =
          *(const float4*)(qk + (size_t)(s * 197 + m) * 384 + 192 + h * 64 + c8 * 8);
    }
    __syncthreads();

    if (has) {
      f4_t S[13];
#pragma unroll
      for (int nt = 0; nt < 13; ++nt) {
        bf8_t k0 = *(const bf8_t*)(Ks + (nt * 16 + mfrag) * 72 + quad * 8);
        bf8_t k1 = *(const bf8_t*)(Ks + (nt * 16 + mfrag) * 72 + 32 + quad * 8);
        f4_t z = (f4_t){0.f, 0.f, 0.f, 0.f};
        z = __builtin_amdgcn_mfma_f32_16x16x32_bf16(qa0, k0, z, 0, 0, 0);
        S[nt] = __builtin_amdgcn_mfma_f32_16x16x32_bf16(qa1, k1, z, 0, 0, 0);
      }
      // exact softmax over keys; lane holds S[q=quad*4+reg][key=nt*16+mfrag]
      float mx[4] = {-1e30f, -1e30f, -1e30f, -1e30f};
#pragma unroll
      for (int nt = 0; nt < 13; ++nt) {
        int key = nt * 16 + mfrag;
#pragma unroll
        for (int reg = 0; reg < 4; ++reg) {
          float v = (key < 197) ? S[nt][reg] * 0.125f : -1e30f;
          S[nt][reg] = v;
          mx[reg] = fmaxf(mx[reg], v);
        }
      }
#pragma unroll
      for (int off = 1; off < 16; off <<= 1)
#pragma unroll
        for (int reg = 0; reg < 4; ++reg) mx[reg] = fmaxf(mx[reg], __shfl_xor(mx[reg], off, 64));
      float sum[4] = {0.f, 0.f, 0.f, 0.f};
#pragma unroll
      for (int nt = 0; nt < 13; ++nt)
#pragma unroll
        for (int reg = 0; reg < 4; ++reg) {
          float p = __expf(S[nt][reg] - mx[reg]);
          S[nt][reg] = p;
          sum[reg] += p;
        }
#pragma unroll
      for (int off = 1; off < 16; off <<= 1)
#pragma unroll
        for (int reg = 0; reg < 4; ++reg) sum[reg] += __shfl_xor(sum[reg], off, 64);
#pragma unroll
      for (int reg = 0; reg < 4; ++reg) sum[reg] = 1.f / sum[reg];
#pragma unroll
      for (int nt = 0; nt < 13; ++nt)
#pragma unroll
        for (int reg = 0; reg < 4; ++reg)
          Pacc[nt][reg] += S[nt][reg] * sum[reg];
    }
  }

  // PV once per strip: Pacc -> LDS (wave-private dbuf) -> A-frag -> MFMA vs V^T
  if (has) {
    f4_t o[4];
#pragma unroll
    for (int dt = 0; dt < 4; ++dt) o[dt] = (f4_t){0.f, 0.f, 0.f, 0.f};
#pragma unroll
    for (int kt = 0; kt < 7; ++kt) {
      unsigned short* buf = Ps[wave][kt & 1];
#pragma unroll
      for (int half = 0; half < 2; ++half) {
        int nt = kt * 2 + half;
#pragma unroll
        for (int reg = 0; reg < 4; ++reg) {
          float p = (nt < 13) ? Pacc[nt][reg] : 0.f;
          buf[(quad * 4 + reg) * 40 + half * 16 + mfrag] = f2bf(p);
        }
      }
      bf8_t pf = *(const bf8_t*)(buf + mfrag * 40 + quad * 8);
#pragma unroll
      for (int dt = 0; dt < 4; ++dt) {
        bf8_t vf = *(const bf8_t*)(Vt + (dt * 16 + mfrag) * 232 + kt * 32 + quad * 8);
        o[dt] = __builtin_amdgcn_mfma_f32_16x16x32_bf16(pf, vf, o[dt], 0, 0, 0);
      }
    }
#pragma unroll
    for (int dt = 0; dt < 4; ++dt)
#pragma unroll
      for (int reg = 0; reg < 4; ++reg) {
        int q = strip * 16 + quad * 4 + reg;
        if (q < 197)
          agg[(size_t)(b * 197 + q) * 192 + h * 64 + dt * 16 + mfrag] = f2bf(o[dt][reg]);
      }
  }
}

// ---------------------------------------------------------------------------
extern "C" void kernel_launch(void* const* d_in, const int* in_sizes, int n_in,
                              void* d_out, int out_size, void* d_ws, size_t ws_size,
                              hipStream_t stream) {
  const float* x      = (const float*)d_in[0];
  const int*   edge   = (const int*)d_in[1];
  const float* n1g    = (const float*)d_in[2];
  const float* n1b    = (const float*)d_in[3];
  const float* qkv_w  = (const float*)d_in[4];
  const float* proj_w = (const float*)d_in[5];
  const float* proj_b = (const float*)d_in[6];
  const float* n2g    = (const float*)d_in[7];
  const float* n2b    = (const float*)d_in[8];
  const float* fc1_w  = (const float*)d_in[9];
  const float* fc1_b  = (const float*)d_in[10];
  const float* fc2_w  = (const float*)d_in[11];
  const float* fc2_b  = (const float*)d_in[12];
  float* out = (float*)d_out;

  char* ws = (char*)d_ws;
  unsigned short* h1     = (unsigned short*)ws;
  unsigned short* qk     = (unsigned short*)(ws + 77463552);
  unsigned short* xn     = (unsigned short*)(ws + 116195328);
  unsigned short* agg    = (unsigned short*)(ws + 135561216);
  unsigned short* vtg    = (unsigned short*)(ws + 154927104);
  unsigned short* wqkv   = (unsigned short*)(ws + 174587904);
  unsigned short* wproj  = (unsigned short*)(ws + 174809088);
  unsigned short* wfc1   = (unsigned short*)(ws + 174882816);
  unsigned short* wfc2   = (unsigned short*)(ws + 175177728);
  int*            cntg   = (int*)           (ws + 175472640);

  dim3 blk(256);
  f2bf_kernel<<<dim3(432), blk, 0, stream>>>(qkv_w, wqkv, 110592);
  f2bf_kernel<<<dim3(144), blk, 0, stream>>>(proj_w, wproj, 36864);
  f2bf_kernel<<<dim3(576), blk, 0, stream>>>(fc1_w, wfc1, 147456);
  f2bf_kernel<<<dim3(576), blk, 0, stream>>>(fc2_w, wfc2, 147456);

  ln_bf16_kernel<<<dim3(12608), blk, 0, stream>>>(x, n1g, n1b, xn);
  gemm_bf16<0, 1><<<dim3(394, 9), blk, 0, stream>>>(xn, wqkv, nullptr, nullptr, nullptr, qk, vtg, 384);
  attn_fused_kernel<<<dim3(256, 3, 4), blk, 0, stream>>>(qk, vtg, edge, agg, cntg);
  gemm_bf16<1, 1><<<dim3(394, 3), blk, 0, stream>>>(agg, wproj, proj_b, x, cntg, out, nullptr, 192);
  ln_bf16_kernel<<<dim3(12608), blk, 0, stream>>>(out, n2g, n2b, xn);
  gemm_bf16<2, 1><<<dim3(394, 12), blk, 0, stream>>>(xn, wfc1, fc1_b, nullptr, nullptr, h1, nullptr, 768);
  gemm_bf16<3, 4><<<dim3(394, 3), blk, 0, stream>>>(h1, wfc2, fc2_b, out, nullptr, out, nullptr, 192);
}